// Round 15
// baseline (38.616 us; speedup 1.0000x reference)
//
#include <hip/hip_runtime.h>
#include <math.h>

#define NFEAT 32
#define EMB   30
#define ATT   10
#define BLK   64    // one wave per block, one batch element per wave
#define ROWP  36    // padded x-row stride (16B-aligned rows, 2-way-bank-free reads)

typedef float f32x4 __attribute__((ext_vector_type(4)));
typedef short bf16x8 __attribute__((ext_vector_type(8)));   // 8 bf16 = 4 VGPR (MFMA A/B frag)
typedef unsigned int u32;

union Frag { u32 u[4]; bf16x8 v; };

__device__ __forceinline__ u32 fbits(float f) { union { float f; u32 u; } c; c.f = f; return c.u; }
__device__ __forceinline__ float fflt(u32 u)  { union { float f; u32 u; } c; c.u = u; return c.f; }

// Split 8 fp32 into hi/lo bf16x8 fragments. hi = round-half-up to bf16,
// lo = (f - hi) truncated to bf16. Dropped residual ~2^-18 rel.
__device__ __forceinline__ void split8(const float4& A, const float4& B, Frag& H, Frag& L) {
    const float xs[8] = {A.x, A.y, A.z, A.w, B.x, B.y, B.z, B.w};
    #pragma unroll
    for (int r = 0; r < 4; ++r) {
        const float f0 = xs[2*r], f1 = xs[2*r+1];
        const u32 h0 = (fbits(f0) + 0x8000u) & 0xffff0000u;
        const u32 h1 = (fbits(f1) + 0x8000u) & 0xffff0000u;
        H.u[r] = (h0 >> 16) | h1;                       // {bf16(f1) : bf16(f0)}
        const float l0 = f0 - fflt(h0);                 // exact (Sterbenz)
        const float l1 = f1 - fflt(h1);
        L.u[r] = (fbits(l0) >> 16) | (fbits(l1) & 0xffff0000u);
    }
}

__device__ __forceinline__ float4 mul4(const float4& a, const float4& b) {
    return make_float4(a.x*b.x, a.y*b.y, a.z*b.z, a.w*b.w);
}

// R15: Gram-form MFMA rewrite. Per batch: Q_a = X Z_a^T (32x32 symmetric,
// Z_a = X .* W[:,a], K=30 padded to 32). 3 useful 16x16 tiles (120+256+120
// = 496 pairs exactly); mfma_f32_16x16x32_bf16 with 2-way bf16 split
// (4 cross terms) -> fp32-grade precision at ~13x the fp32 vector FLOP rate.
// col 10 of the weight block = pvec (gives c values by the same matmul).
__global__ __launch_bounds__(BLK)
void attn_net_kernel(const float* __restrict__ x,
                     const float* __restrict__ W,
                     const float* __restrict__ bias,
                     const float* __restrict__ h,
                     const float* __restrict__ pvec,
                     float* __restrict__ out)
{
    __shared__ __align__(16) float sX[NFEAT * ROWP];    // 4.6 KB, zero-padded cols 30,31
    __shared__ __align__(16) float sW[11 * 32];         // W^T rows 0..9, row 10 = pvec; e>=30 zero

    const int lane = threadIdx.x & 63;
    const int b    = blockIdx.x;

    // ---- stage x[b] (wave-private; scalar scatter as in R7/R14) ----
    {
        const float4* xin = reinterpret_cast<const float4*>(x + (size_t)b * (NFEAT * EMB));
        for (int v = lane; v < 240; v += 64) {          // exactly 240 float4s
            const float4 d = xin[v];
            const int ef = 4 * v;
            #pragma unroll
            for (int u = 0; u < 4; ++u) {
                const int e = ef + u;
                const int r = e / EMB;
                const int c = e - r * EMB;
                sX[r * ROWP + c] = ((const float*)&d)[u];
            }
        }
        if (lane < 32) {                                // K-pad: x cols 30,31 = 0
            sX[lane * ROWP + 30] = 0.f;
            sX[lane * ROWP + 31] = 0.f;
        }
    }
    // ---- stage W^T (+pvec as row 10), K-padded with zeros ----
    for (int q = lane; q < 11 * 32; q += 64) {
        const int a = q >> 5, e = q & 31;
        float v = 0.f;
        if (e < EMB) v = (a < ATT) ? W[e * ATT + a] : pvec[e];
        sW[q] = v;
    }
    __builtin_amdgcn_wave_barrier();                    // wave-private LDS ready

    const int g8  = (lane >> 4) * 8;                    // k-slice base (e = g8..g8+7)
    const int c16 = lane & 15;                          // fragment row/col index

    // ---- this lane's two X row slices (rows c16 and c16+16), fp32 ----
    const float4 xa0 = *reinterpret_cast<const float4*>(&sX[(c16     ) * ROWP + g8]);
    const float4 xb0 = *reinterpret_cast<const float4*>(&sX[(c16     ) * ROWP + g8 + 4]);
    const float4 xa1 = *reinterpret_cast<const float4*>(&sX[(c16 + 16) * ROWP + g8]);
    const float4 xb1 = *reinterpret_cast<const float4*>(&sX[(c16 + 16) * ROWP + g8 + 4]);

    Frag Xh0, Xl0, Xh1, Xl1;                            // A-operand (and x-part of B)
    split8(xa0, xb0, Xh0, Xl0);
    split8(xa1, xb1, Xh1, Xl1);

    float s0[4], s1[4], s2[4];                          // score accum per tile slot
    float c0[4], c1[4], c2[4];                          // pvec-channel values
    #pragma unroll
    for (int r = 0; r < 4; ++r) { s0[r] = 0.f; s1[r] = 0.f; s2[r] = 0.f; }

    #pragma unroll
    for (int a = 0; a < 11; ++a) {                      // 10 attention cols + pvec col
        const float4 w0 = *reinterpret_cast<const float4*>(&sW[a * 32 + g8]);      // broadcast
        const float4 w1 = *reinterpret_cast<const float4*>(&sW[a * 32 + g8 + 4]);

        // Z rows for this lane: z[j,e] = x[j,e] * w[e]  (w=0 at e=30,31 -> pad safe)
        Frag Zh0, Zl0, Zh1, Zl1;
        split8(mul4(xa0, w0), mul4(xb0, w1), Zh0, Zl0);
        split8(mul4(xa1, w0), mul4(xb1, w1), Zh1, Zl1);

        const float ba = (a < ATT) ? bias[a] : 0.f;     // bias folded into accumulator
        f32x4 q00 = {ba, ba, ba, ba};
        f32x4 q01 = {ba, ba, ba, ba};
        f32x4 q11 = {ba, ba, ba, ba};

        // 4-term split product per tile: (Xh+Xl)(Zh+Zl)
        q00 = __builtin_amdgcn_mfma_f32_16x16x32_bf16(Xh0.v, Zh0.v, q00, 0, 0, 0);
        q01 = __builtin_amdgcn_mfma_f32_16x16x32_bf16(Xh0.v, Zh1.v, q01, 0, 0, 0);
        q11 = __builtin_amdgcn_mfma_f32_16x16x32_bf16(Xh1.v, Zh1.v, q11, 0, 0, 0);
        q00 = __builtin_amdgcn_mfma_f32_16x16x32_bf16(Xh0.v, Zl0.v, q00, 0, 0, 0);
        q01 = __builtin_amdgcn_mfma_f32_16x16x32_bf16(Xh0.v, Zl1.v, q01, 0, 0, 0);
        q11 = __builtin_amdgcn_mfma_f32_16x16x32_bf16(Xh1.v, Zl1.v, q11, 0, 0, 0);
        q00 = __builtin_amdgcn_mfma_f32_16x16x32_bf16(Xl0.v, Zh0.v, q00, 0, 0, 0);
        q01 = __builtin_amdgcn_mfma_f32_16x16x32_bf16(Xl0.v, Zh1.v, q01, 0, 0, 0);
        q11 = __builtin_amdgcn_mfma_f32_16x16x32_bf16(Xl1.v, Zh1.v, q11, 0, 0, 0);
        q00 = __builtin_amdgcn_mfma_f32_16x16x32_bf16(Xl0.v, Zl0.v, q00, 0, 0, 0);
        q01 = __builtin_amdgcn_mfma_f32_16x16x32_bf16(Xl0.v, Zl1.v, q01, 0, 0, 0);
        q11 = __builtin_amdgcn_mfma_f32_16x16x32_bf16(Xl1.v, Zl1.v, q11, 0, 0, 0);

        if (a < ATT) {
            const float ha = h[a];
            #pragma unroll
            for (int r = 0; r < 4; ++r) {
                s0[r] = fmaf(fmaxf(q00[r], 0.f), ha, s0[r]);
                s1[r] = fmaf(fmaxf(q01[r], 0.f), ha, s1[r]);
                s2[r] = fmaf(fmaxf(q11[r], 0.f), ha, s2[r]);
            }
        } else {                                        // pvec col: raw Gram values
            #pragma unroll
            for (int r = 0; r < 4; ++r) { c0[r] = q00[r]; c1[r] = q01[r]; c2[r] = q11[r]; }
        }
    }

    // ---- masks: diag tiles valid iff (4g+r) < c16 (symmetric Q -> robust to
    //      operand-order transpose); off-diag tile always valid. 120+256+120=496 ----
    #pragma unroll
    for (int r = 0; r < 4; ++r) {
        const bool valid = ((lane >> 4) * 4 + r) < c16;
        if (!valid) { s0[r] = -INFINITY; s2[r] = -INFINITY; }
    }

    // ---- softmax: max-first, then exp-sums, wave butterflies ----
    float m = s1[0];
    #pragma unroll
    for (int r = 0; r < 4; ++r) {
        m = fmaxf(m, s1[r]);
        m = fmaxf(m, s0[r]);
        m = fmaxf(m, s2[r]);
    }
    #pragma unroll
    for (int o = 1; o < 64; o <<= 1) m = fmaxf(m, __shfl_xor(m, o, 64));

    float se = 0.f, sec = 0.f;
    #pragma unroll
    for (int r = 0; r < 4; ++r) {
        const float E0 = __expf(s0[r] - m);             // exp(-inf)=0 for masked
        const float E1 = __expf(s1[r] - m);
        const float E2 = __expf(s2[r] - m);
        se += E0 + E1 + E2;
        sec = fmaf(E0, c0[r], sec);
        sec = fmaf(E1, c1[r], sec);
        sec = fmaf(E2, c2[r], sec);
    }
    #pragma unroll
    for (int o = 1; o < 64; o <<= 1) {
        se  += __shfl_xor(se,  o, 64);
        sec += __shfl_xor(sec, o, 64);
    }
    if (lane == 0) out[b] = sec / se;
}

extern "C" void kernel_launch(void* const* d_in, const int* in_sizes, int n_in,
                              void* d_out, int out_size, void* d_ws, size_t ws_size,
                              hipStream_t stream) {
    const float* x    = (const float*)d_in[0];
    const float* W    = (const float*)d_in[1];
    const float* bias = (const float*)d_in[2];
    const float* h    = (const float*)d_in[3];
    const float* pvec = (const float*)d_in[4];
    float* out = (float*)d_out;

    const int B = in_sizes[0] / (NFEAT * EMB);   // 8192
    attn_net_kernel<<<B, BLK, 0, stream>>>(x, W, bias, h, pvec, out);
}